// Round 8
// baseline (1272.243 us; speedup 1.0000x reference)
//
#include <hip/hip_runtime.h>

#define VV 4
#define NN 4096
#define HH 128
#define CAP 64
#define R2 16      // rows per block in fused layer2
#define FR 16      // rows per block in fusion
#define CHP (NN / R2)   // 256 column-sum partial chunks per view

typedef __attribute__((ext_vector_type(4))) float fvec4;   // nontemporal-loadable

// ---------------------------------------------------------------------------
// Kernel 1: scan dense adjacency -> per-row neighbor lists + dinv.
// ---------------------------------------------------------------------------
template<int REPS>
__global__ __launch_bounds__(256) void k_build_csr(
    const float* __restrict__ adjs, int* __restrict__ nbr,
    int* __restrict__ cnt, float* __restrict__ dinv)
{
    int wave = threadIdx.x >> 6;
    int lane = threadIdx.x & 63;
    int r = blockIdx.x * 4 + wave;              // global row in [0, V*N)
    const fvec4* row = (const fvec4*)(adjs + (size_t)r * NN);
    int* out = nbr + (size_t)r * CAP;
    unsigned long long lm = (1ull << lane) - 1ull;
    for (int rep = 0; rep < REPS; ++rep) {
        int base = 0;
        #pragma unroll 4
        for (int c = 0; c < NN / 256; ++c) {
            fvec4 x = __builtin_nontemporal_load(&row[c * 64 + lane]);
            int c0 = (x.x != 0.f), c1 = (x.y != 0.f), c2 = (x.z != 0.f), c3 = (x.w != 0.f);
            unsigned long long b0 = __ballot(c0), b1 = __ballot(c1);
            unsigned long long b2 = __ballot(c2), b3 = __ballot(c3);
            int pos = base + __popcll(b0 & lm) + __popcll(b1 & lm)
                           + __popcll(b2 & lm) + __popcll(b3 & lm);
            int e = c * 256 + lane * 4;
            if (c0 && pos < CAP) out[pos] = e;     pos += c0;
            if (c1 && pos < CAP) out[pos] = e + 1; pos += c1;
            if (c2 && pos < CAP) out[pos] = e + 2; pos += c2;
            if (c3 && pos < CAP) out[pos] = e + 3; pos += c3;
            base += __popcll(b0) + __popcll(b1) + __popcll(b2) + __popcll(b3);
        }
        if (lane == 0) {
            cnt[r]  = base < CAP ? base : CAP;
            dinv[r] = rsqrtf((float)(base + 1));   // +1 self loop
        }
    }
}

// ---------------------------------------------------------------------------
// Kernel 2: h1 = relu(A_norm @ w1 + b1).  4 rows per 512-thread block.
// ---------------------------------------------------------------------------
template<int REPS>
__global__ __launch_bounds__(512) void k_spmm1(
    const float* __restrict__ w1, const float* __restrict__ b1,
    const int* __restrict__ nbr, const int* __restrict__ cnt,
    const float* __restrict__ dinv, float* __restrict__ h1)
{
    int g = threadIdx.x >> 7;           // row group 0..3
    int h = threadIdx.x & 127;
    int r = blockIdx.x * 4 + g;         // [0, V*N)
    int v = r >> 12;
    __shared__ int   s_j[4][CAP];
    __shared__ float s_w[4][CAP];
    for (int rep = 0; rep < REPS; ++rep) {
        int n = cnt[r];
        float dr = dinv[r];
        if (h < n) {
            int j = nbr[(size_t)r * CAP + h];
            s_j[g][h] = j;
            s_w[g][h] = dinv[v * NN + j];
        }
        __syncthreads();
        float acc = dr * w1[(size_t)r * HH + h];            // self loop term
        #pragma unroll 4
        for (int k = 0; k < n; ++k)
            acc += s_w[g][k] * w1[((size_t)(v * NN + s_j[g][k])) * HH + h];
        float val = dr * acc + b1[v * HH + h];
        h1[(size_t)r * HH + h] = val > 0.f ? val : 0.f;
        __syncthreads();
    }
}

// ---------------------------------------------------------------------------
// Kernel 3 (fused layer 2): gather u = A_norm@h1, h2 = relu(u@w2+b2),
// plus per-block column partial sums of h2.
// ---------------------------------------------------------------------------
template<int REPS>
__global__ __launch_bounds__(256) void k_layer2(
    const float* __restrict__ h1, const float* __restrict__ w2,
    const float* __restrict__ b2, const int* __restrict__ nbr,
    const int* __restrict__ cnt, const float* __restrict__ dinv,
    float* __restrict__ h2, float* __restrict__ part)
{
    const int bpv = NN / R2;            // 256
    int v = blockIdx.x / bpv;
    int gr0 = blockIdx.x * R2;          // first global row of this block
    __shared__ int   s_n[R2];
    __shared__ float s_dr[R2];
    __shared__ int   s_j[R2][CAP];
    __shared__ float s_w[R2][CAP];
    __shared__ float s_u[R2][HH];
    __shared__ float s_p[8][HH];

    for (int rep = 0; rep < REPS; ++rep) {
        if (threadIdx.x < R2) {
            s_n[threadIdx.x]  = cnt[gr0 + threadIdx.x];
            s_dr[threadIdx.x] = dinv[gr0 + threadIdx.x];
        }
        __syncthreads();
        for (int idx = threadIdx.x; idx < R2 * CAP; idx += 256) {
            int rr = idx >> 6, kk = idx & 63;
            if (kk < s_n[rr]) {
                int j = nbr[(size_t)(gr0 + rr) * CAP + kk];
                s_j[rr][kk] = j;
                s_w[rr][kk] = dinv[v * NN + j];
            }
        }
        __syncthreads();

        {
            int rr  = threadIdx.x >> 4;         // 0..15
            int t16 = threadIdx.x & 15;
            int h0  = t16 * 8;
            int n   = s_n[rr];
            float dr = s_dr[rr];
            const float* self = h1 + (size_t)(gr0 + rr) * HH + h0;
            float a[8];
            #pragma unroll
            for (int q = 0; q < 8; ++q) a[q] = dr * self[q];
            #pragma unroll 2
            for (int k = 0; k < n; ++k) {
                float wj = s_w[rr][k];
                const float4* src = (const float4*)(h1 + ((size_t)(v * NN + s_j[rr][k])) * HH + h0);
                float4 x0 = src[0], x1 = src[1];
                a[0] += wj * x0.x; a[1] += wj * x0.y; a[2] += wj * x0.z; a[3] += wj * x0.w;
                a[4] += wj * x1.x; a[5] += wj * x1.y; a[6] += wj * x1.z; a[7] += wj * x1.w;
            }
            #pragma unroll
            for (int q = 0; q < 8; ++q) s_u[rr][h0 + q] = dr * a[q];
        }
        __syncthreads();

        int r0 = (threadIdx.x >> 5) * 2;        // 0..14
        int c0 = (threadIdx.x & 31) * 4;        // 0..124
        const float* wv = w2 + (size_t)v * HH * HH;
        float acc[2][4];
        #pragma unroll
        for (int i = 0; i < 2; ++i)
            #pragma unroll
            for (int j = 0; j < 4; ++j) acc[i][j] = 0.f;
        for (int k = 0; k < HH; k += 4) {
            float4 a[2], w[4];
            #pragma unroll
            for (int i = 0; i < 2; ++i) a[i] = *(const float4*)&s_u[r0 + i][k];
            #pragma unroll
            for (int kk = 0; kk < 4; ++kk) w[kk] = *(const float4*)&wv[(size_t)(k + kk) * HH + c0];
            #pragma unroll
            for (int i = 0; i < 2; ++i)
                #pragma unroll
                for (int j = 0; j < 4; ++j) {
                    acc[i][j] += a[i].x * ((const float*)&w[0])[j];
                    acc[i][j] += a[i].y * ((const float*)&w[1])[j];
                    acc[i][j] += a[i].z * ((const float*)&w[2])[j];
                    acc[i][j] += a[i].w * ((const float*)&w[3])[j];
                }
        }
        float p[4];
        #pragma unroll
        for (int j = 0; j < 4; ++j) {
            float b = b2[v * HH + c0 + j];
            float v0 = acc[0][j] + b, v1 = acc[1][j] + b;
            v0 = v0 > 0.f ? v0 : 0.f;
            v1 = v1 > 0.f ? v1 : 0.f;
            acc[0][j] = v0; acc[1][j] = v1;
            p[j] = v0 + v1;
        }
        #pragma unroll
        for (int i = 0; i < 2; ++i) {
            float4 o = { acc[i][0], acc[i][1], acc[i][2], acc[i][3] };
            *(float4*)&h2[(size_t)(gr0 + r0 + i) * HH + c0] = o;
        }
        *(float4*)&s_p[threadIdx.x >> 5][c0] = *(float4*)p;
        __syncthreads();
        if (threadIdx.x < HH) {
            float a = 0.f;
            #pragma unroll
            for (int q = 0; q < 8; ++q) a += s_p[q][threadIdx.x];
            part[(size_t)blockIdx.x * HH + threadIdx.x] = a;
        }
        __syncthreads();
    }
}

// ---------------------------------------------------------------------------
// Kernel 4: finish summaries, attention MLP, softmax. Single block (512 thr).
// ---------------------------------------------------------------------------
template<int REPS>
__global__ __launch_bounds__(512) void k_attn(
    const float* __restrict__ part, const float* __restrict__ wa1,
    const float* __restrict__ ba1, const float* __restrict__ wa2,
    const float* __restrict__ ba2, float* __restrict__ attn_out,
    float* __restrict__ attn_ws)
{
    __shared__ float s_sum[VV * HH];
    __shared__ float s_red[256];
    __shared__ float s_score[VV];
    for (int rep = 0; rep < REPS; ++rep) {
        {
            int v = threadIdx.x >> 7, h = threadIdx.x & 127;   // 512 = 4*128
            float a = 0.f;
            #pragma unroll 8
            for (int c = 0; c < CHP; ++c) a += part[(size_t)(v * CHP + c) * HH + h];
            s_sum[v * HH + h] = a * (1.0f / NN);     // mean over N
        }
        __syncthreads();
        if (threadIdx.x < 256) {
            int v = threadIdx.x >> 6, u = threadIdx.x & 63;
            float a = ba1[u];
            for (int k = 0; k < HH; ++k) a += s_sum[v * HH + k] * wa1[k * 64 + u];
            s_red[threadIdx.x] = tanhf(a) * wa2[u];
        }
        __syncthreads();
        if (threadIdx.x < VV) {
            float sc = ba2[0];
            for (int uu = 0; uu < 64; ++uu) sc += s_red[threadIdx.x * 64 + uu];
            s_score[threadIdx.x] = sc;
        }
        __syncthreads();
        if (threadIdx.x == 0) {
            float m = s_score[0];
            for (int i = 1; i < VV; ++i) m = fmaxf(m, s_score[i]);
            float e[VV], den = 0.f;
            for (int i = 0; i < VV; ++i) { e[i] = __expf(s_score[i] - m); den += e[i]; }
            for (int i = 0; i < VV; ++i) {
                float av = e[i] / den;
                attn_out[i] = av;
                attn_ws[i]  = av;
            }
        }
        __syncthreads();
    }
}

// ---------------------------------------------------------------------------
// Kernel 5: fusion MLP v2 (unchanged from R6).
// ---------------------------------------------------------------------------
#define S1 516     // s_in row stride (floats)
#define S2 260     // s_hid / s_part row stride
#define S3 132     // gemm2 partial row stride
__global__ __launch_bounds__(512) void k_fusion(
    const float* __restrict__ h2, const float* __restrict__ attn_ws,
    const float* __restrict__ wf1, const float* __restrict__ bf1,
    const float* __restrict__ wf2, const float* __restrict__ bf2,
    float* __restrict__ fused)
{
    __shared__ float s_in[FR][S1];      // 33 KB (also aliased as s_part/s_p2)
    __shared__ float s_hid[FR][S2];     // 16.6 KB
    float (*s_part)[S2] = (float (*)[S2])&s_in[0][0];
    float (*s_p2)[S3]   = (float (*)[S3])&s_in[0][0];

    int nbase = blockIdx.x * FR;
    int wv   = threadIdx.x >> 6;
    int lane = threadIdx.x & 63;
    float at[VV];
    #pragma unroll
    for (int v = 0; v < VV; ++v) at[v] = attn_ws[v];

    for (int idx = threadIdx.x; idx < FR * 128; idx += 512) {
        int r  = idx >> 7;
        int c4 = idx & 127;
        int v  = c4 >> 5;
        int h4 = c4 & 31;
        const float4* srcr = (const float4*)(h2 + ((size_t)v * NN + nbase + r) * HH);
        float4 x = srcr[h4];
        float s = at[v];
        x.x *= s; x.y *= s; x.z *= s; x.w *= s;
        *(float4*)&s_in[r][c4 * 4] = x;
    }
    __syncthreads();

    int cg = wv & 3, kh = wv >> 2;
    int ccol  = cg * 64 + (lane & 15) * 4;   // [0,256)
    int rbase = (lane >> 4) * 4;             // 0,4,8,12
    float acc[4][4];
    #pragma unroll
    for (int i = 0; i < 4; ++i)
        #pragma unroll
        for (int j = 0; j < 4; ++j) acc[i][j] = 0.f;
    {
        int k0 = kh * 256;
        const float* wrow = wf1 + (size_t)k0 * 256 + ccol;
        #pragma unroll 4
        for (int k = 0; k < 256; ++k) {
            float4 wk = *(const float4*)wrow;
            wrow += 256;
            float a0 = s_in[rbase + 0][k0 + k];
            float a1 = s_in[rbase + 1][k0 + k];
            float a2 = s_in[rbase + 2][k0 + k];
            float a3 = s_in[rbase + 3][k0 + k];
            acc[0][0] += a0 * wk.x; acc[0][1] += a0 * wk.y; acc[0][2] += a0 * wk.z; acc[0][3] += a0 * wk.w;
            acc[1][0] += a1 * wk.x; acc[1][1] += a1 * wk.y; acc[1][2] += a1 * wk.z; acc[1][3] += a1 * wk.w;
            acc[2][0] += a2 * wk.x; acc[2][1] += a2 * wk.y; acc[2][2] += a2 * wk.z; acc[2][3] += a2 * wk.w;
            acc[3][0] += a3 * wk.x; acc[3][1] += a3 * wk.y; acc[3][2] += a3 * wk.z; acc[3][3] += a3 * wk.w;
        }
    }
    __syncthreads();
    if (kh == 1) {
        #pragma unroll
        for (int i = 0; i < 4; ++i)
            *(float4*)&s_part[rbase + i][ccol] = *(float4*)&acc[i][0];
    }
    __syncthreads();
    if (kh == 0) {
        float4 b = *(const float4*)&bf1[ccol];
        #pragma unroll
        for (int i = 0; i < 4; ++i) {
            float4 p = *(float4*)&s_part[rbase + i][ccol];
            float h0 = acc[i][0] + p.x + b.x;
            float h1v = acc[i][1] + p.y + b.y;
            float h2v = acc[i][2] + p.z + b.z;
            float h3 = acc[i][3] + p.w + b.w;
            float4 o;
            o.x = h0 > 0.f ? h0 : 0.f;
            o.y = h1v > 0.f ? h1v : 0.f;
            o.z = h2v > 0.f ? h2v : 0.f;
            o.w = h3 > 0.f ? h3 : 0.f;
            *(float4*)&s_hid[rbase + i][ccol] = o;
        }
    }
    __syncthreads();

    int cg2 = wv & 3, kh2 = wv >> 2;
    int c2 = cg2 * 32 + (lane & 15) * 2;     // [0,128)
    float acc2[4][2];
    #pragma unroll
    for (int i = 0; i < 4; ++i) { acc2[i][0] = 0.f; acc2[i][1] = 0.f; }
    {
        int k0 = kh2 * 128;
        const float* wrow = wf2 + (size_t)k0 * 128 + c2;
        #pragma unroll 4
        for (int k = 0; k < 128; ++k) {
            float2 wk = *(const float2*)wrow;
            wrow += 128;
            #pragma unroll
            for (int i = 0; i < 4; ++i) {
                float a = s_hid[rbase + i][k0 + k];
                acc2[i][0] += a * wk.x;
                acc2[i][1] += a * wk.y;
            }
        }
    }
    __syncthreads();
    if (kh2 == 1) {
        #pragma unroll
        for (int i = 0; i < 4; ++i) {
            float2 o = { acc2[i][0], acc2[i][1] };
            *(float2*)&s_p2[rbase + i][c2] = o;
        }
    }
    __syncthreads();
    if (kh2 == 0) {
        float b0 = bf2[c2], b1 = bf2[c2 + 1];
        #pragma unroll
        for (int i = 0; i < 4; ++i) {
            float2 p = *(float2*)&s_p2[rbase + i][c2];
            float2 o = { acc2[i][0] + p.x + b0, acc2[i][1] + p.y + b1 };
            *(float2*)&fused[(size_t)(nbase + rbase + i) * HH + c2] = o;
        }
    }
}

// ---------------------------------------------------------------------------
// MEASUREMENT ROUND 2: pipeline byte-identical; three same-tier probes
// (spmm1 x32, layer2 x24, attn x64) into ws sinks so top-5 shows a mix of
// their counter rows. dur_us is a throwaway.
// ---------------------------------------------------------------------------
extern "C" void kernel_launch(void* const* d_in, const int* in_sizes, int n_in,
                              void* d_out, int out_size, void* d_ws, size_t ws_size,
                              hipStream_t stream)
{
    const float* adjs = (const float*)d_in[0];
    const float* w1   = (const float*)d_in[1];
    const float* b1   = (const float*)d_in[2];
    const float* w2   = (const float*)d_in[3];
    const float* b2   = (const float*)d_in[4];
    const float* wa1  = (const float*)d_in[5];
    const float* ba1  = (const float*)d_in[6];
    const float* wa2  = (const float*)d_in[7];
    const float* ba2  = (const float*)d_in[8];
    const float* wf1  = (const float*)d_in[9];
    const float* bf1  = (const float*)d_in[10];
    const float* wf2  = (const float*)d_in[11];
    const float* bf2  = (const float*)d_in[12];

    float* out   = (float*)d_out;
    float* fused = out;                        // [N, 128]
    float* attn  = out + (size_t)NN * HH;      // [V]
    float* h2    = attn + VV;                  // [V, N, H]

    char* w = (char*)d_ws;
    int*   nbr    = (int*)w;    w += (size_t)VV * NN * CAP * sizeof(int);
    int*   cnt    = (int*)w;    w += (size_t)VV * NN * sizeof(int);
    float* dinv   = (float*)w;  w += (size_t)VV * NN * sizeof(float);
    float* h1     = (float*)w;  w += (size_t)VV * NN * HH * sizeof(float);
    float* part   = (float*)w;  w += (size_t)VV * CHP * HH * sizeof(float);
    float* attnws = (float*)w;  w += 256;
    // probe sinks
    float* h1_s   = (float*)w;  w += (size_t)VV * NN * HH * sizeof(float);
    float* h2_s   = (float*)w;  w += (size_t)VV * NN * HH * sizeof(float);
    float* part_s = (float*)w;  w += (size_t)VV * CHP * HH * sizeof(float);
    float* attn_s = (float*)w;  w += 256;
    float* aws_s  = (float*)w;  w += 256;

    // ---- validated pipeline (byte-identical to R7) ----
    k_build_csr<1><<<VV * NN / 4, 256, 0, stream>>>(adjs, nbr, cnt, dinv);
    k_spmm1<1><<<VV * NN / 4, 512, 0, stream>>>(w1, b1, nbr, cnt, dinv, h1);
    k_layer2<1><<<VV * NN / R2, 256, 0, stream>>>(h1, w2, b2, nbr, cnt, dinv, h2, part);
    k_attn<1><<<1, 512, 0, stream>>>(part, wa1, ba1, wa2, ba2, attn, attnws);
    k_fusion<<<NN / FR, 512, 0, stream>>>(h2, attnws, wf1, bf1, wf2, bf2, fused);

    // ---- probes (read pipeline buffers, write sinks) ----
    k_spmm1<32><<<VV * NN / 4, 512, 0, stream>>>(w1, b1, nbr, cnt, dinv, h1_s);
    k_layer2<24><<<VV * NN / R2, 256, 0, stream>>>(h1, w2, b2, nbr, cnt, dinv, h2_s, part_s);
    k_attn<64><<<1, 512, 0, stream>>>(part, wa1, ba1, wa2, ba2, attn_s, aws_s);
}

// Round 9
// 594.418 us; speedup vs baseline: 2.1403x; 2.1403x over previous
//
#include <hip/hip_runtime.h>

#define VV 4
#define NN 4096
#define HH 128
#define CAP 64
#define R2 16      // rows per block in fused layer2
#define FR 16      // rows per block in fusion
#define CHP (NN / R2)   // 256 column-sum partial chunks per view

typedef __attribute__((ext_vector_type(4))) float fvec4;   // nontemporal-loadable

// ---------------------------------------------------------------------------
// Kernel 1: scan dense adjacency -> per-row neighbor lists + dinv.
// ---------------------------------------------------------------------------
template<int REPS>
__global__ __launch_bounds__(256) void k_build_csr(
    const float* __restrict__ adjs, int* __restrict__ nbr,
    int* __restrict__ cnt, float* __restrict__ dinv)
{
    int wave = threadIdx.x >> 6;
    int lane = threadIdx.x & 63;
    int r = blockIdx.x * 4 + wave;              // global row in [0, V*N)
    const fvec4* row = (const fvec4*)(adjs + (size_t)r * NN);
    int* out = nbr + (size_t)r * CAP;
    unsigned long long lm = (1ull << lane) - 1ull;
    for (int rep = 0; rep < REPS; ++rep) {
        int base = 0;
        #pragma unroll 4
        for (int c = 0; c < NN / 256; ++c) {
            fvec4 x = __builtin_nontemporal_load(&row[c * 64 + lane]);
            int c0 = (x.x != 0.f), c1 = (x.y != 0.f), c2 = (x.z != 0.f), c3 = (x.w != 0.f);
            unsigned long long b0 = __ballot(c0), b1 = __ballot(c1);
            unsigned long long b2 = __ballot(c2), b3 = __ballot(c3);
            int pos = base + __popcll(b0 & lm) + __popcll(b1 & lm)
                           + __popcll(b2 & lm) + __popcll(b3 & lm);
            int e = c * 256 + lane * 4;
            if (c0 && pos < CAP) out[pos] = e;     pos += c0;
            if (c1 && pos < CAP) out[pos] = e + 1; pos += c1;
            if (c2 && pos < CAP) out[pos] = e + 2; pos += c2;
            if (c3 && pos < CAP) out[pos] = e + 3; pos += c3;
            base += __popcll(b0) + __popcll(b1) + __popcll(b2) + __popcll(b3);
        }
        if (lane == 0) {
            cnt[r]  = base < CAP ? base : CAP;
            dinv[r] = rsqrtf((float)(base + 1));   // +1 self loop
        }
    }
}

// ---------------------------------------------------------------------------
// Kernel 2: h1 = relu(A_norm @ w1 + b1).  4 rows per 512-thread block.
// XCD-swizzled: view v's blocks pinned to XCDs {2v,2v+1} so the 2 MB w1
// view-slice stays L2-resident per XCD (blockIdx%8 -> XCD round-robin).
// ---------------------------------------------------------------------------
__global__ __launch_bounds__(512) void k_spmm1(
    const float* __restrict__ w1, const float* __restrict__ b1,
    const int* __restrict__ nbr, const int* __restrict__ cnt,
    const float* __restrict__ dinv, float* __restrict__ h1)
{
    // bijective remap: 4096 blocks = 512 slots x 8 xcds
    int xcd  = blockIdx.x & 7;
    int slot = blockIdx.x >> 3;            // 0..511
    int wid  = (xcd >> 1) * 1024 + slot * 2 + (xcd & 1);
    int g = threadIdx.x >> 7;              // row group 0..3
    int h = threadIdx.x & 127;
    int r = wid * 4 + g;                   // [0, V*N)
    int v = r >> 12;
    __shared__ int   s_j[4][CAP];
    __shared__ float s_w[4][CAP];
    int n = cnt[r];
    float dr = dinv[r];
    if (h < n) {
        int j = nbr[(size_t)r * CAP + h];
        s_j[g][h] = j;
        s_w[g][h] = dinv[v * NN + j];
    }
    __syncthreads();
    float acc = dr * w1[(size_t)r * HH + h];            // self loop term
    #pragma unroll 4
    for (int k = 0; k < n; ++k)
        acc += s_w[g][k] * w1[((size_t)(v * NN + s_j[g][k])) * HH + h];
    float val = dr * acc + b1[v * HH + h];
    h1[(size_t)r * HH + h] = val > 0.f ? val : 0.f;
}

// ---------------------------------------------------------------------------
// Kernel 3 (fused layer 2): gather u = A_norm@h1, h2 = relu(u@w2+b2),
// plus per-block column partial sums of h2.  XCD-swizzled like spmm1 so each
// XCD's L2 holds its view's 2 MB h1 slice. s_u written via float4 (b128).
// ---------------------------------------------------------------------------
template<int REPS>
__global__ __launch_bounds__(256) void k_layer2(
    const float* __restrict__ h1, const float* __restrict__ w2,
    const float* __restrict__ b2, const int* __restrict__ nbr,
    const int* __restrict__ cnt, const float* __restrict__ dinv,
    float* __restrict__ h2, float* __restrict__ part)
{
    // bijective remap: 1024 blocks = 128 slots x 8 xcds; view = xcd>>1
    int xcd  = blockIdx.x & 7;
    int slot = blockIdx.x >> 3;            // 0..127
    int wid  = (xcd >> 1) * 256 + slot * 2 + (xcd & 1);
    int v   = wid >> 8;                    // wid/256
    int gr0 = wid * R2;                    // first global row of this block
    __shared__ int   s_n[R2];
    __shared__ float s_dr[R2];
    __shared__ int   s_j[R2][CAP];
    __shared__ float s_w[R2][CAP];
    __shared__ float s_u[R2][HH];
    __shared__ float s_p[8][HH];

    for (int rep = 0; rep < REPS; ++rep) {
        if (threadIdx.x < R2) {
            s_n[threadIdx.x]  = cnt[gr0 + threadIdx.x];
            s_dr[threadIdx.x] = dinv[gr0 + threadIdx.x];
        }
        __syncthreads();
        for (int idx = threadIdx.x; idx < R2 * CAP; idx += 256) {
            int rr = idx >> 6, kk = idx & 63;
            if (kk < s_n[rr]) {
                int j = nbr[(size_t)(gr0 + rr) * CAP + kk];
                s_j[rr][kk] = j;
                s_w[rr][kk] = dinv[v * NN + j];
            }
        }
        __syncthreads();

        {
            int rr  = threadIdx.x >> 4;         // 0..15
            int t16 = threadIdx.x & 15;
            int h0  = t16 * 8;
            int n   = s_n[rr];
            float dr = s_dr[rr];
            const float* self = h1 + (size_t)(gr0 + rr) * HH + h0;
            float a[8];
            #pragma unroll
            for (int q = 0; q < 8; ++q) a[q] = dr * self[q];
            #pragma unroll 4
            for (int k = 0; k < n; ++k) {
                float wj = s_w[rr][k];
                const float4* src = (const float4*)(h1 + ((size_t)(v * NN + s_j[rr][k])) * HH + h0);
                float4 x0 = src[0], x1 = src[1];
                a[0] += wj * x0.x; a[1] += wj * x0.y; a[2] += wj * x0.z; a[3] += wj * x0.w;
                a[4] += wj * x1.x; a[5] += wj * x1.y; a[6] += wj * x1.z; a[7] += wj * x1.w;
            }
            float4 o0 = { dr * a[0], dr * a[1], dr * a[2], dr * a[3] };
            float4 o1 = { dr * a[4], dr * a[5], dr * a[6], dr * a[7] };
            *(float4*)&s_u[rr][h0]     = o0;
            *(float4*)&s_u[rr][h0 + 4] = o1;
        }
        __syncthreads();

        int r0 = (threadIdx.x >> 5) * 2;        // 0..14
        int c0 = (threadIdx.x & 31) * 4;        // 0..124
        const float* wv = w2 + (size_t)v * HH * HH;
        float acc[2][4];
        #pragma unroll
        for (int i = 0; i < 2; ++i)
            #pragma unroll
            for (int j = 0; j < 4; ++j) acc[i][j] = 0.f;
        for (int k = 0; k < HH; k += 4) {
            float4 a[2], w[4];
            #pragma unroll
            for (int i = 0; i < 2; ++i) a[i] = *(const float4*)&s_u[r0 + i][k];
            #pragma unroll
            for (int kk = 0; kk < 4; ++kk) w[kk] = *(const float4*)&wv[(size_t)(k + kk) * HH + c0];
            #pragma unroll
            for (int i = 0; i < 2; ++i)
                #pragma unroll
                for (int j = 0; j < 4; ++j) {
                    acc[i][j] += a[i].x * ((const float*)&w[0])[j];
                    acc[i][j] += a[i].y * ((const float*)&w[1])[j];
                    acc[i][j] += a[i].z * ((const float*)&w[2])[j];
                    acc[i][j] += a[i].w * ((const float*)&w[3])[j];
                }
        }
        float p[4];
        #pragma unroll
        for (int j = 0; j < 4; ++j) {
            float b = b2[v * HH + c0 + j];
            float v0 = acc[0][j] + b, v1 = acc[1][j] + b;
            v0 = v0 > 0.f ? v0 : 0.f;
            v1 = v1 > 0.f ? v1 : 0.f;
            acc[0][j] = v0; acc[1][j] = v1;
            p[j] = v0 + v1;
        }
        #pragma unroll
        for (int i = 0; i < 2; ++i) {
            float4 o = { acc[i][0], acc[i][1], acc[i][2], acc[i][3] };
            *(float4*)&h2[(size_t)(gr0 + r0 + i) * HH + c0] = o;
        }
        *(float4*)&s_p[threadIdx.x >> 5][c0] = *(float4*)p;
        __syncthreads();
        if (threadIdx.x < HH) {
            float a = 0.f;
            #pragma unroll
            for (int q = 0; q < 8; ++q) a += s_p[q][threadIdx.x];
            part[(size_t)wid * HH + threadIdx.x] = a;
        }
        __syncthreads();
    }
}

// ---------------------------------------------------------------------------
// Kernel 4: finish summaries, attention MLP, softmax. Single block (512 thr).
// ---------------------------------------------------------------------------
__global__ __launch_bounds__(512) void k_attn(
    const float* __restrict__ part, const float* __restrict__ wa1,
    const float* __restrict__ ba1, const float* __restrict__ wa2,
    const float* __restrict__ ba2, float* __restrict__ attn_out,
    float* __restrict__ attn_ws)
{
    __shared__ float s_sum[VV * HH];
    __shared__ float s_red[256];
    __shared__ float s_score[VV];
    {
        int v = threadIdx.x >> 7, h = threadIdx.x & 127;   // 512 = 4*128
        float a = 0.f;
        #pragma unroll 8
        for (int c = 0; c < CHP; ++c) a += part[(size_t)(v * CHP + c) * HH + h];
        s_sum[v * HH + h] = a * (1.0f / NN);     // mean over N
    }
    __syncthreads();
    if (threadIdx.x < 256) {
        int v = threadIdx.x >> 6, u = threadIdx.x & 63;
        float a = ba1[u];
        for (int k = 0; k < HH; ++k) a += s_sum[v * HH + k] * wa1[k * 64 + u];
        s_red[threadIdx.x] = tanhf(a) * wa2[u];
    }
    __syncthreads();
    if (threadIdx.x < VV) {
        float sc = ba2[0];
        for (int uu = 0; uu < 64; ++uu) sc += s_red[threadIdx.x * 64 + uu];
        s_score[threadIdx.x] = sc;
    }
    __syncthreads();
    if (threadIdx.x == 0) {
        float m = s_score[0];
        for (int i = 1; i < VV; ++i) m = fmaxf(m, s_score[i]);
        float e[VV], den = 0.f;
        for (int i = 0; i < VV; ++i) { e[i] = __expf(s_score[i] - m); den += e[i]; }
        for (int i = 0; i < VV; ++i) {
            float av = e[i] / den;
            attn_out[i] = av;
            attn_ws[i]  = av;
        }
    }
}

// ---------------------------------------------------------------------------
// Kernel 5: fusion MLP v2 (unchanged from R6).
// ---------------------------------------------------------------------------
#define S1 516     // s_in row stride (floats)
#define S2 260     // s_hid / s_part row stride
#define S3 132     // gemm2 partial row stride
__global__ __launch_bounds__(512) void k_fusion(
    const float* __restrict__ h2, const float* __restrict__ attn_ws,
    const float* __restrict__ wf1, const float* __restrict__ bf1,
    const float* __restrict__ wf2, const float* __restrict__ bf2,
    float* __restrict__ fused)
{
    __shared__ float s_in[FR][S1];      // 33 KB (also aliased as s_part/s_p2)
    __shared__ float s_hid[FR][S2];     // 16.6 KB
    float (*s_part)[S2] = (float (*)[S2])&s_in[0][0];
    float (*s_p2)[S3]   = (float (*)[S3])&s_in[0][0];

    int nbase = blockIdx.x * FR;
    int wv   = threadIdx.x >> 6;
    int lane = threadIdx.x & 63;
    float at[VV];
    #pragma unroll
    for (int v = 0; v < VV; ++v) at[v] = attn_ws[v];

    for (int idx = threadIdx.x; idx < FR * 128; idx += 512) {
        int r  = idx >> 7;
        int c4 = idx & 127;
        int v  = c4 >> 5;
        int h4 = c4 & 31;
        const float4* srcr = (const float4*)(h2 + ((size_t)v * NN + nbase + r) * HH);
        float4 x = srcr[h4];
        float s = at[v];
        x.x *= s; x.y *= s; x.z *= s; x.w *= s;
        *(float4*)&s_in[r][c4 * 4] = x;
    }
    __syncthreads();

    int cg = wv & 3, kh = wv >> 2;
    int ccol  = cg * 64 + (lane & 15) * 4;   // [0,256)
    int rbase = (lane >> 4) * 4;             // 0,4,8,12
    float acc[4][4];
    #pragma unroll
    for (int i = 0; i < 4; ++i)
        #pragma unroll
        for (int j = 0; j < 4; ++j) acc[i][j] = 0.f;
    {
        int k0 = kh * 256;
        const float* wrow = wf1 + (size_t)k0 * 256 + ccol;
        #pragma unroll 4
        for (int k = 0; k < 256; ++k) {
            float4 wk = *(const float4*)wrow;
            wrow += 256;
            float a0 = s_in[rbase + 0][k0 + k];
            float a1 = s_in[rbase + 1][k0 + k];
            float a2 = s_in[rbase + 2][k0 + k];
            float a3 = s_in[rbase + 3][k0 + k];
            acc[0][0] += a0 * wk.x; acc[0][1] += a0 * wk.y; acc[0][2] += a0 * wk.z; acc[0][3] += a0 * wk.w;
            acc[1][0] += a1 * wk.x; acc[1][1] += a1 * wk.y; acc[1][2] += a1 * wk.z; acc[1][3] += a1 * wk.w;
            acc[2][0] += a2 * wk.x; acc[2][1] += a2 * wk.y; acc[2][2] += a2 * wk.z; acc[2][3] += a2 * wk.w;
            acc[3][0] += a3 * wk.x; acc[3][1] += a3 * wk.y; acc[3][2] += a3 * wk.z; acc[3][3] += a3 * wk.w;
        }
    }
    __syncthreads();
    if (kh == 1) {
        #pragma unroll
        for (int i = 0; i < 4; ++i)
            *(float4*)&s_part[rbase + i][ccol] = *(float4*)&acc[i][0];
    }
    __syncthreads();
    if (kh == 0) {
        float4 b = *(const float4*)&bf1[ccol];
        #pragma unroll
        for (int i = 0; i < 4; ++i) {
            float4 p = *(float4*)&s_part[rbase + i][ccol];
            float h0 = acc[i][0] + p.x + b.x;
            float h1v = acc[i][1] + p.y + b.y;
            float h2v = acc[i][2] + p.z + b.z;
            float h3 = acc[i][3] + p.w + b.w;
            float4 o;
            o.x = h0 > 0.f ? h0 : 0.f;
            o.y = h1v > 0.f ? h1v : 0.f;
            o.z = h2v > 0.f ? h2v : 0.f;
            o.w = h3 > 0.f ? h3 : 0.f;
            *(float4*)&s_hid[rbase + i][ccol] = o;
        }
    }
    __syncthreads();

    int cg2 = wv & 3, kh2 = wv >> 2;
    int c2 = cg2 * 32 + (lane & 15) * 2;     // [0,128)
    float acc2[4][2];
    #pragma unroll
    for (int i = 0; i < 4; ++i) { acc2[i][0] = 0.f; acc2[i][1] = 0.f; }
    {
        int k0 = kh2 * 128;
        const float* wrow = wf2 + (size_t)k0 * 128 + c2;
        #pragma unroll 4
        for (int k = 0; k < 128; ++k) {
            float2 wk = *(const float2*)wrow;
            wrow += 128;
            #pragma unroll
            for (int i = 0; i < 4; ++i) {
                float a = s_hid[rbase + i][k0 + k];
                acc2[i][0] += a * wk.x;
                acc2[i][1] += a * wk.y;
            }
        }
    }
    __syncthreads();
    if (kh2 == 1) {
        #pragma unroll
        for (int i = 0; i < 4; ++i) {
            float2 o = { acc2[i][0], acc2[i][1] };
            *(float2*)&s_p2[rbase + i][c2] = o;
        }
    }
    __syncthreads();
    if (kh2 == 0) {
        float b0 = bf2[c2], b1 = bf2[c2 + 1];
        #pragma unroll
        for (int i = 0; i < 4; ++i) {
            float2 p = *(float2*)&s_p2[rbase + i][c2];
            float2 o = { acc2[i][0] + p.x + b0, acc2[i][1] + p.y + b1 };
            *(float2*)&fused[(size_t)(nbase + rbase + i) * HH + c2] = o;
        }
    }
}

// ---------------------------------------------------------------------------
extern "C" void kernel_launch(void* const* d_in, const int* in_sizes, int n_in,
                              void* d_out, int out_size, void* d_ws, size_t ws_size,
                              hipStream_t stream)
{
    const float* adjs = (const float*)d_in[0];
    const float* w1   = (const float*)d_in[1];
    const float* b1   = (const float*)d_in[2];
    const float* w2   = (const float*)d_in[3];
    const float* b2   = (const float*)d_in[4];
    const float* wa1  = (const float*)d_in[5];
    const float* ba1  = (const float*)d_in[6];
    const float* wa2  = (const float*)d_in[7];
    const float* ba2  = (const float*)d_in[8];
    const float* wf1  = (const float*)d_in[9];
    const float* bf1  = (const float*)d_in[10];
    const float* wf2  = (const float*)d_in[11];
    const float* bf2  = (const float*)d_in[12];

    float* out   = (float*)d_out;
    float* fused = out;                        // [N, 128]
    float* attn  = out + (size_t)NN * HH;      // [V]
    float* h2    = attn + VV;                  // [V, N, H]

    char* w = (char*)d_ws;
    int*   nbr    = (int*)w;    w += (size_t)VV * NN * CAP * sizeof(int);
    int*   cnt    = (int*)w;    w += (size_t)VV * NN * sizeof(int);
    float* dinv   = (float*)w;  w += (size_t)VV * NN * sizeof(float);
    float* h1     = (float*)w;  w += (size_t)VV * NN * HH * sizeof(float);
    float* part   = (float*)w;  w += (size_t)VV * CHP * HH * sizeof(float);
    float* attnws = (float*)w;  w += 256;
    // probe sinks
    float* h2_s   = (float*)w;  w += (size_t)VV * NN * HH * sizeof(float);
    float* part_s = (float*)w;  w += (size_t)VV * CHP * HH * sizeof(float);

    // ---- validated pipeline ----
    k_build_csr<1><<<VV * NN / 4, 256, 0, stream>>>(adjs, nbr, cnt, dinv);
    k_spmm1<<<VV * NN / 4, 512, 0, stream>>>(w1, b1, nbr, cnt, dinv, h1);
    k_layer2<1><<<VV * NN / R2, 256, 0, stream>>>(h1, w2, b2, nbr, cnt, dinv, h2, part);
    k_attn<<<1, 512, 0, stream>>>(part, wa1, ba1, wa2, ba2, attn, attnws);
    k_fusion<<<NN / FR, 512, 0, stream>>>(h2, attnws, wf1, bf1, wf2, bf2, fused);

    // ---- probe: verify the layer2 fix with its own counter row ----
    k_layer2<24><<<VV * NN / R2, 256, 0, stream>>>(h1, w2, b2, nbr, cnt, dinv, h2_s, part_s);
}

// Round 10
// 134.908 us; speedup vs baseline: 9.4305x; 4.4061x over previous
//
#include <hip/hip_runtime.h>

#define VV 4
#define NN 4096
#define HH 128
#define CAP 64
#define R2 16      // rows per block in fused layer2
#define FR 16      // rows per block in fusion
#define CHP (NN / R2)   // 256 column-sum partial chunks per view

typedef __attribute__((ext_vector_type(4))) float fvec4;   // nontemporal-loadable

// ---------------------------------------------------------------------------
// Kernel 1: scan dense adjacency -> per-row neighbor lists + dinv.
// ---------------------------------------------------------------------------
__global__ __launch_bounds__(256) void k_build_csr(
    const float* __restrict__ adjs, int* __restrict__ nbr,
    int* __restrict__ cnt, float* __restrict__ dinv)
{
    int wave = threadIdx.x >> 6;
    int lane = threadIdx.x & 63;
    int r = blockIdx.x * 4 + wave;              // global row in [0, V*N)
    const fvec4* row = (const fvec4*)(adjs + (size_t)r * NN);
    int* out = nbr + (size_t)r * CAP;
    unsigned long long lm = (1ull << lane) - 1ull;
    int base = 0;
    #pragma unroll 4
    for (int c = 0; c < NN / 256; ++c) {
        fvec4 x = __builtin_nontemporal_load(&row[c * 64 + lane]);
        int c0 = (x.x != 0.f), c1 = (x.y != 0.f), c2 = (x.z != 0.f), c3 = (x.w != 0.f);
        unsigned long long b0 = __ballot(c0), b1 = __ballot(c1);
        unsigned long long b2 = __ballot(c2), b3 = __ballot(c3);
        int pos = base + __popcll(b0 & lm) + __popcll(b1 & lm)
                       + __popcll(b2 & lm) + __popcll(b3 & lm);
        int e = c * 256 + lane * 4;
        if (c0 && pos < CAP) out[pos] = e;     pos += c0;
        if (c1 && pos < CAP) out[pos] = e + 1; pos += c1;
        if (c2 && pos < CAP) out[pos] = e + 2; pos += c2;
        if (c3 && pos < CAP) out[pos] = e + 3; pos += c3;
        base += __popcll(b0) + __popcll(b1) + __popcll(b2) + __popcll(b3);
    }
    if (lane == 0) {
        cnt[r]  = base < CAP ? base : CAP;
        dinv[r] = rsqrtf((float)(base + 1));   // +1 self loop
    }
}

// ---------------------------------------------------------------------------
// Kernel 2: h1 = relu(A_norm @ w1 + b1).  4 rows per 512-thread block.
// XCD-swizzled: view v's blocks pinned to XCDs {2v,2v+1}.
// ---------------------------------------------------------------------------
__global__ __launch_bounds__(512) void k_spmm1(
    const float* __restrict__ w1, const float* __restrict__ b1,
    const int* __restrict__ nbr, const int* __restrict__ cnt,
    const float* __restrict__ dinv, float* __restrict__ h1)
{
    // bijective remap: 4096 blocks = 512 slots x 8 xcds
    int xcd  = blockIdx.x & 7;
    int slot = blockIdx.x >> 3;            // 0..511
    int wid  = (xcd >> 1) * 1024 + slot * 2 + (xcd & 1);
    int g = threadIdx.x >> 7;              // row group 0..3
    int h = threadIdx.x & 127;
    int r = wid * 4 + g;                   // [0, V*N)
    int v = r >> 12;
    __shared__ int   s_j[4][CAP];
    __shared__ float s_w[4][CAP];
    int n = cnt[r];
    float dr = dinv[r];
    if (h < n) {
        int j = nbr[(size_t)r * CAP + h];
        s_j[g][h] = j;
        s_w[g][h] = dinv[v * NN + j];
    }
    __syncthreads();
    float acc = dr * w1[(size_t)r * HH + h];            // self loop term
    #pragma unroll 4
    for (int k = 0; k < n; ++k)
        acc += s_w[g][k] * w1[((size_t)(v * NN + s_j[g][k])) * HH + h];
    float val = dr * acc + b1[v * HH + h];
    h1[(size_t)r * HH + h] = val > 0.f ? val : 0.f;
}

// ---------------------------------------------------------------------------
// Kernel 3 (fused layer 2): gather u = A_norm@h1, h2 = relu(u@w2+b2),
// plus per-block column partial sums of h2.  XCD-swizzled.
// ---------------------------------------------------------------------------
__global__ __launch_bounds__(256) void k_layer2(
    const float* __restrict__ h1, const float* __restrict__ w2,
    const float* __restrict__ b2, const int* __restrict__ nbr,
    const int* __restrict__ cnt, const float* __restrict__ dinv,
    float* __restrict__ h2, float* __restrict__ part)
{
    // bijective remap: 1024 blocks = 128 slots x 8 xcds; view = xcd>>1
    int xcd  = blockIdx.x & 7;
    int slot = blockIdx.x >> 3;            // 0..127
    int wid  = (xcd >> 1) * 256 + slot * 2 + (xcd & 1);
    int v   = wid >> 8;                    // wid/256
    int gr0 = wid * R2;                    // first global row of this block
    __shared__ int   s_n[R2];
    __shared__ float s_dr[R2];
    __shared__ int   s_j[R2][CAP];
    __shared__ float s_w[R2][CAP];
    __shared__ float s_u[R2][HH];
    __shared__ float s_p[8][HH];

    if (threadIdx.x < R2) {
        s_n[threadIdx.x]  = cnt[gr0 + threadIdx.x];
        s_dr[threadIdx.x] = dinv[gr0 + threadIdx.x];
    }
    __syncthreads();
    for (int idx = threadIdx.x; idx < R2 * CAP; idx += 256) {
        int rr = idx >> 6, kk = idx & 63;
        if (kk < s_n[rr]) {
            int j = nbr[(size_t)(gr0 + rr) * CAP + kk];
            s_j[rr][kk] = j;
            s_w[rr][kk] = dinv[v * NN + j];
        }
    }
    __syncthreads();

    {
        int rr  = threadIdx.x >> 4;         // 0..15
        int t16 = threadIdx.x & 15;
        int h0  = t16 * 8;
        int n   = s_n[rr];
        float dr = s_dr[rr];
        const float* self = h1 + (size_t)(gr0 + rr) * HH + h0;
        float a[8];
        #pragma unroll
        for (int q = 0; q < 8; ++q) a[q] = dr * self[q];
        #pragma unroll 4
        for (int k = 0; k < n; ++k) {
            float wj = s_w[rr][k];
            const float4* src = (const float4*)(h1 + ((size_t)(v * NN + s_j[rr][k])) * HH + h0);
            float4 x0 = src[0], x1 = src[1];
            a[0] += wj * x0.x; a[1] += wj * x0.y; a[2] += wj * x0.z; a[3] += wj * x0.w;
            a[4] += wj * x1.x; a[5] += wj * x1.y; a[6] += wj * x1.z; a[7] += wj * x1.w;
        }
        float4 o0 = { dr * a[0], dr * a[1], dr * a[2], dr * a[3] };
        float4 o1 = { dr * a[4], dr * a[5], dr * a[6], dr * a[7] };
        *(float4*)&s_u[rr][h0]     = o0;
        *(float4*)&s_u[rr][h0 + 4] = o1;
    }
    __syncthreads();

    int r0 = (threadIdx.x >> 5) * 2;        // 0..14
    int c0 = (threadIdx.x & 31) * 4;        // 0..124
    const float* wv = w2 + (size_t)v * HH * HH;
    float acc[2][4];
    #pragma unroll
    for (int i = 0; i < 2; ++i)
        #pragma unroll
        for (int j = 0; j < 4; ++j) acc[i][j] = 0.f;
    for (int k = 0; k < HH; k += 4) {
        float4 a[2], w[4];
        #pragma unroll
        for (int i = 0; i < 2; ++i) a[i] = *(const float4*)&s_u[r0 + i][k];
        #pragma unroll
        for (int kk = 0; kk < 4; ++kk) w[kk] = *(const float4*)&wv[(size_t)(k + kk) * HH + c0];
        #pragma unroll
        for (int i = 0; i < 2; ++i)
            #pragma unroll
            for (int j = 0; j < 4; ++j) {
                acc[i][j] += a[i].x * ((const float*)&w[0])[j];
                acc[i][j] += a[i].y * ((const float*)&w[1])[j];
                acc[i][j] += a[i].z * ((const float*)&w[2])[j];
                acc[i][j] += a[i].w * ((const float*)&w[3])[j];
            }
    }
    float p[4];
    #pragma unroll
    for (int j = 0; j < 4; ++j) {
        float b = b2[v * HH + c0 + j];
        float v0 = acc[0][j] + b, v1 = acc[1][j] + b;
        v0 = v0 > 0.f ? v0 : 0.f;
        v1 = v1 > 0.f ? v1 : 0.f;
        acc[0][j] = v0; acc[1][j] = v1;
        p[j] = v0 + v1;
    }
    #pragma unroll
    for (int i = 0; i < 2; ++i) {
        float4 o = { acc[i][0], acc[i][1], acc[i][2], acc[i][3] };
        *(float4*)&h2[(size_t)(gr0 + r0 + i) * HH + c0] = o;
    }
    *(float4*)&s_p[threadIdx.x >> 5][c0] = *(float4*)p;
    __syncthreads();
    if (threadIdx.x < HH) {
        float a = 0.f;
        #pragma unroll
        for (int q = 0; q < 8; ++q) a += s_p[q][threadIdx.x];
        part[(size_t)wid * HH + threadIdx.x] = a;
    }
}

// ---------------------------------------------------------------------------
// Kernel 4: finish summaries, attention MLP, softmax. Single block (512 thr).
// ---------------------------------------------------------------------------
__global__ __launch_bounds__(512) void k_attn(
    const float* __restrict__ part, const float* __restrict__ wa1,
    const float* __restrict__ ba1, const float* __restrict__ wa2,
    const float* __restrict__ ba2, float* __restrict__ attn_out,
    float* __restrict__ attn_ws)
{
    __shared__ float s_sum[VV * HH];
    __shared__ float s_red[256];
    __shared__ float s_score[VV];
    {
        int v = threadIdx.x >> 7, h = threadIdx.x & 127;   // 512 = 4*128
        float a = 0.f;
        #pragma unroll 8
        for (int c = 0; c < CHP; ++c) a += part[(size_t)(v * CHP + c) * HH + h];
        s_sum[v * HH + h] = a * (1.0f / NN);     // mean over N
    }
    __syncthreads();
    if (threadIdx.x < 256) {
        int v = threadIdx.x >> 6, u = threadIdx.x & 63;
        float a = ba1[u];
        for (int k = 0; k < HH; ++k) a += s_sum[v * HH + k] * wa1[k * 64 + u];
        s_red[threadIdx.x] = tanhf(a) * wa2[u];
    }
    __syncthreads();
    if (threadIdx.x < VV) {
        float sc = ba2[0];
        for (int uu = 0; uu < 64; ++uu) sc += s_red[threadIdx.x * 64 + uu];
        s_score[threadIdx.x] = sc;
    }
    __syncthreads();
    if (threadIdx.x == 0) {
        float m = s_score[0];
        for (int i = 1; i < VV; ++i) m = fmaxf(m, s_score[i]);
        float e[VV], den = 0.f;
        for (int i = 0; i < VV; ++i) { e[i] = __expf(s_score[i] - m); den += e[i]; }
        for (int i = 0; i < VV; ++i) {
            float av = e[i] / den;
            attn_out[i] = av;
            attn_ws[i]  = av;
        }
    }
}

// ---------------------------------------------------------------------------
// Kernel 5: fusion MLP v2.
// ---------------------------------------------------------------------------
#define S1 516     // s_in row stride (floats)
#define S2 260     // s_hid / s_part row stride
#define S3 132     // gemm2 partial row stride
__global__ __launch_bounds__(512) void k_fusion(
    const float* __restrict__ h2, const float* __restrict__ attn_ws,
    const float* __restrict__ wf1, const float* __restrict__ bf1,
    const float* __restrict__ wf2, const float* __restrict__ bf2,
    float* __restrict__ fused)
{
    __shared__ float s_in[FR][S1];      // 33 KB (also aliased as s_part/s_p2)
    __shared__ float s_hid[FR][S2];     // 16.6 KB
    float (*s_part)[S2] = (float (*)[S2])&s_in[0][0];
    float (*s_p2)[S3]   = (float (*)[S3])&s_in[0][0];

    int nbase = blockIdx.x * FR;
    int wv   = threadIdx.x >> 6;
    int lane = threadIdx.x & 63;
    float at[VV];
    #pragma unroll
    for (int v = 0; v < VV; ++v) at[v] = attn_ws[v];

    for (int idx = threadIdx.x; idx < FR * 128; idx += 512) {
        int r  = idx >> 7;
        int c4 = idx & 127;
        int v  = c4 >> 5;
        int h4 = c4 & 31;
        const float4* srcr = (const float4*)(h2 + ((size_t)v * NN + nbase + r) * HH);
        float4 x = srcr[h4];
        float s = at[v];
        x.x *= s; x.y *= s; x.z *= s; x.w *= s;
        *(float4*)&s_in[r][c4 * 4] = x;
    }
    __syncthreads();

    int cg = wv & 3, kh = wv >> 2;
    int ccol  = cg * 64 + (lane & 15) * 4;   // [0,256)
    int rbase = (lane >> 4) * 4;             // 0,4,8,12
    float acc[4][4];
    #pragma unroll
    for (int i = 0; i < 4; ++i)
        #pragma unroll
        for (int j = 0; j < 4; ++j) acc[i][j] = 0.f;
    {
        int k0 = kh * 256;
        const float* wrow = wf1 + (size_t)k0 * 256 + ccol;
        #pragma unroll 4
        for (int k = 0; k < 256; ++k) {
            float4 wk = *(const float4*)wrow;
            wrow += 256;
            float a0 = s_in[rbase + 0][k0 + k];
            float a1 = s_in[rbase + 1][k0 + k];
            float a2 = s_in[rbase + 2][k0 + k];
            float a3 = s_in[rbase + 3][k0 + k];
            acc[0][0] += a0 * wk.x; acc[0][1] += a0 * wk.y; acc[0][2] += a0 * wk.z; acc[0][3] += a0 * wk.w;
            acc[1][0] += a1 * wk.x; acc[1][1] += a1 * wk.y; acc[1][2] += a1 * wk.z; acc[1][3] += a1 * wk.w;
            acc[2][0] += a2 * wk.x; acc[2][1] += a2 * wk.y; acc[2][2] += a2 * wk.z; acc[2][3] += a2 * wk.w;
            acc[3][0] += a3 * wk.x; acc[3][1] += a3 * wk.y; acc[3][2] += a3 * wk.z; acc[3][3] += a3 * wk.w;
        }
    }
    __syncthreads();
    if (kh == 1) {
        #pragma unroll
        for (int i = 0; i < 4; ++i)
            *(float4*)&s_part[rbase + i][ccol] = *(float4*)&acc[i][0];
    }
    __syncthreads();
    if (kh == 0) {
        float4 b = *(const float4*)&bf1[ccol];
        #pragma unroll
        for (int i = 0; i < 4; ++i) {
            float4 p = *(float4*)&s_part[rbase + i][ccol];
            float h0 = acc[i][0] + p.x + b.x;
            float h1v = acc[i][1] + p.y + b.y;
            float h2v = acc[i][2] + p.z + b.z;
            float h3 = acc[i][3] + p.w + b.w;
            float4 o;
            o.x = h0 > 0.f ? h0 : 0.f;
            o.y = h1v > 0.f ? h1v : 0.f;
            o.z = h2v > 0.f ? h2v : 0.f;
            o.w = h3 > 0.f ? h3 : 0.f;
            *(float4*)&s_hid[rbase + i][ccol] = o;
        }
    }
    __syncthreads();

    int cg2 = wv & 3, kh2 = wv >> 2;
    int c2 = cg2 * 32 + (lane & 15) * 2;     // [0,128)
    float acc2[4][2];
    #pragma unroll
    for (int i = 0; i < 4; ++i) { acc2[i][0] = 0.f; acc2[i][1] = 0.f; }
    {
        int k0 = kh2 * 128;
        const float* wrow = wf2 + (size_t)k0 * 128 + c2;
        #pragma unroll 4
        for (int k = 0; k < 128; ++k) {
            float2 wk = *(const float2*)wrow;
            wrow += 128;
            #pragma unroll
            for (int i = 0; i < 4; ++i) {
                float a = s_hid[rbase + i][k0 + k];
                acc2[i][0] += a * wk.x;
                acc2[i][1] += a * wk.y;
            }
        }
    }
    __syncthreads();
    if (kh2 == 1) {
        #pragma unroll
        for (int i = 0; i < 4; ++i) {
            float2 o = { acc2[i][0], acc2[i][1] };
            *(float2*)&s_p2[rbase + i][c2] = o;
        }
    }
    __syncthreads();
    if (kh2 == 0) {
        float b0 = bf2[c2], b1 = bf2[c2 + 1];
        #pragma unroll
        for (int i = 0; i < 4; ++i) {
            float2 p = *(float2*)&s_p2[rbase + i][c2];
            float2 o = { acc2[i][0] + p.x + b0, acc2[i][1] + p.y + b1 };
            *(float2*)&fused[(size_t)(nbase + rbase + i) * HH + c2] = o;
        }
    }
}

// ---------------------------------------------------------------------------
// CLEAN ROUND: R9 pipeline byte-identical, probes removed. Honest headline.
// ---------------------------------------------------------------------------
extern "C" void kernel_launch(void* const* d_in, const int* in_sizes, int n_in,
                              void* d_out, int out_size, void* d_ws, size_t ws_size,
                              hipStream_t stream)
{
    const float* adjs = (const float*)d_in[0];
    const float* w1   = (const float*)d_in[1];
    const float* b1   = (const float*)d_in[2];
    const float* w2   = (const float*)d_in[3];
    const float* b2   = (const float*)d_in[4];
    const float* wa1  = (const float*)d_in[5];
    const float* ba1  = (const float*)d_in[6];
    const float* wa2  = (const float*)d_in[7];
    const float* ba2  = (const float*)d_in[8];
    const float* wf1  = (const float*)d_in[9];
    const float* bf1  = (const float*)d_in[10];
    const float* wf2  = (const float*)d_in[11];
    const float* bf2  = (const float*)d_in[12];

    float* out   = (float*)d_out;
    float* fused = out;                        // [N, 128]
    float* attn  = out + (size_t)NN * HH;      // [V]
    float* h2    = attn + VV;                  // [V, N, H]

    char* w = (char*)d_ws;
    int*   nbr    = (int*)w;    w += (size_t)VV * NN * CAP * sizeof(int);
    int*   cnt    = (int*)w;    w += (size_t)VV * NN * sizeof(int);
    float* dinv   = (float*)w;  w += (size_t)VV * NN * sizeof(float);
    float* h1     = (float*)w;  w += (size_t)VV * NN * HH * sizeof(float);
    float* part   = (float*)w;  w += (size_t)VV * CHP * HH * sizeof(float);
    float* attnws = (float*)w;  w += 256;

    k_build_csr<<<VV * NN / 4, 256, 0, stream>>>(adjs, nbr, cnt, dinv);
    k_spmm1<<<VV * NN / 4, 512, 0, stream>>>(w1, b1, nbr, cnt, dinv, h1);
    k_layer2<<<VV * NN / R2, 256, 0, stream>>>(h1, w2, b2, nbr, cnt, dinv, h2, part);
    k_attn<<<1, 512, 0, stream>>>(part, wa1, ba1, wa2, ba2, attn, attnws);
    k_fusion<<<NN / FR, 512, 0, stream>>>(h2, attnws, wf1, bf1, wf2, bf2, fused);
}